// Round 6
// baseline (214.839 us; speedup 1.0000x reference)
//
#include <hip/hip_runtime.h>
#include <math.h>

#define D 64
#define EPSN 1e-12f
#define SCAN_B 256
#define RPB 128          // rows per bucket
#define RPB_SH 7
#define CH 4096          // edges per phase-1 workgroup
#define NBK_CAP 1024     // scan-padded bucket capacity (NBK=782 for N=100000)
#define CAP 4096         // LDS edge capacity per bucket in k_p2f (mean 2048, sigma 45)

__device__ __forceinline__ float bf2f(unsigned short u) {
    return __uint_as_float((unsigned)u << 16);
}
__device__ __forceinline__ unsigned short f2bf(float f) {
    unsigned u = __float_as_uint(f);
    u = (u + 0x7FFFu + ((u >> 16) & 1u)) >> 16;      // RNE fp32 -> bf16
    return (unsigned short)u;
}

// ---------- K1: fused: [0,xnb) xn-normalize; [xnb,..) degree histogram ----------
__global__ __launch_bounds__(256) void k_xn_hist(const float4* __restrict__ x4,
                                                 ushort4* __restrict__ xnh4,
                                                 const int* __restrict__ row,
                                                 int* __restrict__ deg,
                                                 int N, int E, int xnb) {
    if ((int)blockIdx.x < xnb) {
        int tid = blockIdx.x * 256 + threadIdx.x;
        int r = tid >> 4;
        int g = tid & 15;
        if (r >= N) return;
        float4 v = x4[(size_t)r * 16 + g];
        float s = v.x * v.x + v.y * v.y + v.z * v.z + v.w * v.w;
        #pragma unroll
        for (int off = 8; off; off >>= 1) s += __shfl_xor(s, off);
        float inv = 1.0f / fmaxf(sqrtf(s), EPSN);
        ushort4 o;
        o.x = f2bf(v.x * inv); o.y = f2bf(v.y * inv);
        o.z = f2bf(v.z * inv); o.w = f2bf(v.w * inv);
        xnh4[(size_t)r * 16 + g] = o;
    } else {
        int i = (blockIdx.x - xnb) * 256 + threadIdx.x;
        int e = i * 4;
        if (e + 3 < E) {
            int4 r = *(const int4*)(row + e);
            atomicAdd(&deg[r.x], 1); atomicAdd(&deg[r.y], 1);
            atomicAdd(&deg[r.z], 1); atomicAdd(&deg[r.w], 1);
        } else {
            for (int k = e; k < E; ++k) atomicAdd(&deg[row[k]], 1);
        }
    }
}

// ---------- K2: per-block exclusive scan of deg -> rs ----------
__global__ void k_scan1(const int* __restrict__ deg, int* __restrict__ rs,
                        int* __restrict__ bsums, int N) {
    __shared__ int sm[SCAN_B];
    int i = blockIdx.x * SCAN_B + threadIdx.x;
    int v = (i < N) ? deg[i] : 0;
    sm[threadIdx.x] = v;
    __syncthreads();
    for (int off = 1; off < SCAN_B; off <<= 1) {
        int add = (threadIdx.x >= off) ? sm[threadIdx.x - off] : 0;
        __syncthreads();
        sm[threadIdx.x] += add;
        __syncthreads();
    }
    if (i < N) rs[i] = sm[threadIdx.x] - v;
    if (threadIdx.x == SCAN_B - 1) bsums[blockIdx.x] = sm[threadIdx.x];
}

// ---------- K3: single-block scan of block sums ----------
__global__ void k_scan2(int* __restrict__ bsums, int NB) {
    __shared__ int sm[1024];
    int t = threadIdx.x;
    int v = (t < NB) ? bsums[t] : 0;
    sm[t] = v;
    __syncthreads();
    for (int off = 1; off < 1024; off <<= 1) {
        int add = (t >= off) ? sm[t - off] : 0;
        __syncthreads();
        sm[t] += add;
        __syncthreads();
    }
    if (t < NB) bsums[t] = sm[t] - v;
}

// ---------- K4: finalize rs; init bucket cursors to bucket segment bases ----------
__global__ void k_scan3(int* __restrict__ rs, const int* __restrict__ bsums,
                        int* __restrict__ bcur, int N, int E) {
    int i = blockIdx.x * blockDim.x + threadIdx.x;
    if (i == 0) rs[N] = E;
    if (i >= N) return;
    int v = rs[i] + bsums[i / SCAN_B];
    rs[i] = v;
    if ((i & (RPB - 1)) == 0) bcur[i >> RPB_SH] = v;
}

// ---------- K5: phase-1 LDS multi-split: bucket-grouped {ea, rl|col} ----------
__global__ __launch_bounds__(256) void k_p1(const int* __restrict__ row,
                                            const int* __restrict__ col,
                                            const float* __restrict__ ea,
                                            int* __restrict__ gcur,
                                            float2* __restrict__ p1, int E, int NBK) {
    __shared__ unsigned hist[NBK_CAP];       // becomes loff after in-place scan
    __shared__ unsigned gb[NBK_CAP];
    __shared__ unsigned lcur[NBK_CAP];
    __shared__ float    sea[CH];
    __shared__ unsigned spk[CH];
    __shared__ unsigned short sbk[CH];
    __shared__ unsigned temp[256];

    int tid  = threadIdx.x;
    int base = blockIdx.x * CH;
    int cnt  = min(CH, E - base);

    for (int b = tid; b < NBK_CAP; b += 256) hist[b] = 0;
    __syncthreads();

    int   myrow[16]; int mycol[16]; float myea[16];
    #pragma unroll
    for (int k = 0; k < 16; ++k) {
        int j = tid + k * 256;
        if (j < cnt) {
            int r = row[base + j];
            myrow[k] = r;
            mycol[k] = col[base + j];
            myea[k]  = ea[base + j];
            atomicAdd(&hist[r >> RPB_SH], 1u);
        }
    }
    __syncthreads();

    for (int b = tid; b < NBK; b += 256) {
        unsigned c = hist[b];
        gb[b] = c ? (unsigned)atomicAdd(&gcur[b], (int)c) : 0u;
    }
    __syncthreads();

    int t4 = tid * 4;
    unsigned a0 = hist[t4], a1 = hist[t4 + 1], a2 = hist[t4 + 2], a3 = hist[t4 + 3];
    unsigned ts = a0 + a1 + a2 + a3;
    temp[tid] = ts;
    __syncthreads();
    for (int off = 1; off < 256; off <<= 1) {
        unsigned add = (tid >= off) ? temp[tid - off] : 0;
        __syncthreads();
        temp[tid] += add;
        __syncthreads();
    }
    unsigned tb = temp[tid] - ts;
    hist[t4] = tb; hist[t4 + 1] = tb + a0;
    hist[t4 + 2] = tb + a0 + a1; hist[t4 + 3] = tb + a0 + a1 + a2;
    __syncthreads();
    for (int b = tid; b < NBK_CAP; b += 256) lcur[b] = hist[b];
    __syncthreads();

    #pragma unroll
    for (int k = 0; k < 16; ++k) {
        int j = tid + k * 256;
        if (j < cnt) {
            int b = myrow[k] >> RPB_SH;
            unsigned rl = (unsigned)(myrow[k] & (RPB - 1));
            unsigned pos = atomicAdd(&lcur[b], 1u);
            sea[pos] = myea[k];
            spk[pos] = (rl << 24) | (unsigned)mycol[k];
            sbk[pos] = (unsigned short)b;
        }
    }
    __syncthreads();

    for (int j = tid; j < cnt; j += 256) {
        int b = sbk[j];
        unsigned gpos = gb[b] + (unsigned)j - hist[b];   // hist == loff
        p1[gpos] = make_float2(sea[j], __uint_as_float(spk[j]));
    }
}

// ---------- K6: fused per-bucket: row norms + LDS row-sort + softmax-SpMM + residual ----------
__global__ __launch_bounds__(256) void k_p2f(const int* __restrict__ rs,
                                             const float2* __restrict__ p1,
                                             const unsigned short* __restrict__ xnh,
                                             const float* __restrict__ x,
                                             const float* __restrict__ beta,
                                             const float* __restrict__ eps,
                                             float* __restrict__ out, int N) {
    __shared__ float    lea[CAP];
    __shared__ unsigned lcol[CAP];
    __shared__ float    sqs[RPB];
    __shared__ float    binv[RPB];
    __shared__ unsigned cur[RPB];
    __shared__ unsigned roff[RPB + 1];
    __shared__ float    facc[4][64];
    __shared__ float    fes[4];

    int b = blockIdx.x;
    int tid = threadIdx.x;
    int rowbase = b << RPB_SH;
    int nrows = min(RPB, N - rowbase);
    int s = rs[rowbase];
    int t = rs[rowbase + nrows];
    int cnt = t - s;

    if (tid < RPB) sqs[tid] = 0.0f;
    __syncthreads();
    // pass 1: per-row ||ea||^2 from the bucket's contiguous global segment
    for (int j = s + tid; j < t; j += 256) {
        float a = p1[j].x;
        unsigned rl = __float_as_uint(p1[j].y) >> 24;
        atomicAdd(&sqs[rl], a * a);
    }
    __syncthreads();
    float bv = beta[0];
    float ev = eps[0];
    float ebv = __expf(bv);
    if (tid < RPB) binv[tid] = bv / fmaxf(sqrtf(sqs[tid]), EPSN);
    if (tid <= nrows) roff[tid] = (unsigned)(rs[rowbase + tid] - s);
    if (tid < nrows) cur[tid] = (unsigned)(rs[rowbase + tid] - s);
    __syncthreads();

    int wv = tid >> 6, lane = tid & 63;

    if (cnt <= CAP) {
        // pass 2: row-sort {ea,col} into LDS (bucket segment is L2-hot from pass 1)
        for (int j = s + tid; j < t; j += 256) {
            float2 p = p1[j];
            unsigned pk = __float_as_uint(p.y);
            unsigned rl = pk >> 24;
            unsigned pos = atomicAdd(&cur[rl], 1u);
            lea[pos]  = p.x;
            lcol[pos] = pk & 0xFFFFFFu;
        }
        __syncthreads();
        // pass 3: wave per row: softmax-weighted gather + residual
        for (int r = wv; r < nrows; r += 4) {
            int ls = roff[r], le = roff[r + 1];
            float bi = binv[r];
            float esum = 0.0f, acc = 0.0f;
            int k = ls;
            for (; k + 4 <= le; k += 4) {
                unsigned c0 = lcol[k], c1 = lcol[k + 1], c2 = lcol[k + 2], c3 = lcol[k + 3];
                float x0 = bf2f(xnh[(size_t)c0 * D + lane]);
                float x1 = bf2f(xnh[(size_t)c1 * D + lane]);
                float x2 = bf2f(xnh[(size_t)c2 * D + lane]);
                float x3 = bf2f(xnh[(size_t)c3 * D + lane]);
                float w0 = __expf(lea[k] * bi),     w1 = __expf(lea[k + 1] * bi);
                float w2 = __expf(lea[k + 2] * bi), w3 = __expf(lea[k + 3] * bi);
                esum += (w0 + w1) + (w2 + w3);
                acc = fmaf(w0, x0, fmaf(w1, x1, fmaf(w2, x2, fmaf(w3, x3, acc))));
            }
            for (; k < le; ++k) {
                float w0 = __expf(lea[k] * bi);
                esum += w0;
                acc = fmaf(w0, bf2f(xnh[(size_t)lcol[k] * D + lane]), acc);
            }
            int gr = rowbase + r;
            float v = x[(size_t)gr * D + lane];
            float ss = v * v;
            #pragma unroll
            for (int off = 32; off; off >>= 1) ss += __shfl_xor(ss, off);
            float xs = v * (1.0f / fmaxf(sqrtf(ss), EPSN));
            float invden = 1.0f / (esum + ebv);
            out[(size_t)gr * D + lane] = (1.0f + ev) * xs + (acc + ebv * xs) * invden;
        }
    } else {
        // slow path (statistically unreachable for this input; correct for any input)
        for (int r = 0; r < nrows; ++r) {
            float bi = binv[r];
            float esum = 0.0f, acc = 0.0f;
            for (int j = s + wv; j < t; j += 4) {
                float2 p = p1[j];
                unsigned pk = __float_as_uint(p.y);
                if ((pk >> 24) == (unsigned)r) {
                    float w = __expf(p.x * bi);
                    esum += w;
                    acc = fmaf(w, bf2f(xnh[(size_t)(pk & 0xFFFFFFu) * D + lane]), acc);
                }
            }
            facc[wv][lane] = acc;
            if (lane == 0) fes[wv] = esum;
            __syncthreads();
            if (wv == 0) {
                acc  = facc[0][lane] + facc[1][lane] + facc[2][lane] + facc[3][lane];
                esum = fes[0] + fes[1] + fes[2] + fes[3];
                int gr = rowbase + r;
                float v = x[(size_t)gr * D + lane];
                float ss = v * v;
                #pragma unroll
                for (int off = 32; off; off >>= 1) ss += __shfl_xor(ss, off);
                float xs = v * (1.0f / fmaxf(sqrtf(ss), EPSN));
                float invden = 1.0f / (esum + ebv);
                out[(size_t)gr * D + lane] = (1.0f + ev) * xs + (acc + ebv * xs) * invden;
            }
            __syncthreads();
        }
    }
}

static inline size_t align_up(size_t v, size_t a) { return (v + a - 1) & ~(a - 1); }

extern "C" void kernel_launch(void* const* d_in, const int* in_sizes, int n_in,
                              void* d_out, int out_size, void* d_ws, size_t ws_size,
                              hipStream_t stream) {
    const float* x    = (const float*)d_in[0];
    const int*   ei   = (const int*)d_in[1];
    const float* ea   = (const float*)d_in[2];
    const float* eps  = (const float*)d_in[3];
    const float* beta = (const float*)d_in[4];
    float* out = (float*)d_out;

    int N = in_sizes[0] / D;
    int E = in_sizes[2];
    const int* row = ei;
    const int* col = ei + E;
    int NBK = (N + RPB - 1) >> RPB_SH;

    char* base = (char*)d_ws;
    size_t off = 0;
    unsigned short* xnh = (unsigned short*)(base + off); off = align_up(off + (size_t)N * D * sizeof(unsigned short), 256);
    int*    deg_cur     = (int*)(base + off);            off = align_up(off + (size_t)N * sizeof(int), 256);  // deg, then bucket cursors
    int*    rs          = (int*)(base + off);            off = align_up(off + (size_t)(N + 1) * sizeof(int), 256);
    int*    bsums       = (int*)(base + off);            off = align_up(off + 1024 * sizeof(int), 256);
    float2* p1buf       = (float2*)(base + off);

    hipMemsetAsync(deg_cur, 0, (size_t)N * sizeof(int), stream);

    const int B = 256;
    int xn_blocks   = ((size_t)N * 16 + B - 1) / B;
    int hist_blocks = ((E + 3) / 4 + B - 1) / B;
    int node_blocks = (N + B - 1) / B;
    int p1_blocks   = (E + CH - 1) / CH;
    int NB = (N + SCAN_B - 1) / SCAN_B;

    k_xn_hist<<<xn_blocks + hist_blocks, B, 0, stream>>>((const float4*)x, (ushort4*)xnh,
                                                         row, deg_cur, N, E, xn_blocks);
    k_scan1  <<<NB, SCAN_B, 0, stream>>>(deg_cur, rs, bsums, N);
    k_scan2  <<<1, 1024, 0, stream>>>(bsums, NB);
    k_scan3  <<<node_blocks, B, 0, stream>>>(rs, bsums, deg_cur, N, E);
    k_p1     <<<p1_blocks, B, 0, stream>>>(row, col, ea, deg_cur, p1buf, E, NBK);
    k_p2f    <<<NBK, B, 0, stream>>>(rs, p1buf, xnh, x, beta, eps, out, N);
}